// Round 1
// baseline (291.378 us; speedup 1.0000x reference)
//
#include <hip/hip_runtime.h>

// AirFitMultiHeadDNN: per item b:
//   ev[h]   = emb[e[b,h]]                        (3)
//   fv[h]   = f[b,h,:] @ Wf + bf                 (5)
//   x[h]    = [ev, fv]                           (8)
//   h1[h]   = leaky_relu(x @ W1[h] + b1[h])      (10)
//   s[h]    = softplus(h1 . W2[h] + b2[h])
//   out[b]  = sum_h s[h]*Wo[h] + bo
//
// Design: one thread per item. Inputs (20 int + 60 float) loaded with
// int4/float4 vector loads, head loop fully unrolled so rows live in
// registers. All weights are wave-uniform and read from global with
// constant offsets through const __restrict__ pointers -> compiler emits
// s_load into SGPRs (no LDS broadcast cost, no VGPR cost). Only the
// divergent embedding gather uses LDS (rows padded to 4 floats).

#define HH   20
#define NEX  13

__global__ __launch_bounds__(256) void airfit_kernel(
    const int*   __restrict__ e,   const float* __restrict__ f,
    const float* __restrict__ emb, const float* __restrict__ Wf,
    const float* __restrict__ bf,  const float* __restrict__ W1,
    const float* __restrict__ b1,  const float* __restrict__ W2,
    const float* __restrict__ b2,  const float* __restrict__ Wo,
    const float* __restrict__ bo,  float* __restrict__ out, int B)
{
    __shared__ float s_emb[NEX * 4];   // rows padded to 4 floats
    if (threadIdx.x < NEX * 3) {
        int r = threadIdx.x / 3;
        int c = threadIdx.x - r * 3;
        s_emb[r * 4 + c] = emb[threadIdx.x];
    }
    __syncthreads();

    int b = blockIdx.x * 256 + threadIdx.x;
    if (b >= B) return;

    // ---- load input rows (vectorized, constant-indexed -> stay in VGPRs) ----
    int er[HH];
    {
        const int4* ep = reinterpret_cast<const int4*>(e + (size_t)b * HH);
#pragma unroll
        for (int j = 0; j < 5; ++j) {
            int4 v = ep[j];
            er[4 * j + 0] = v.x; er[4 * j + 1] = v.y;
            er[4 * j + 2] = v.z; er[4 * j + 3] = v.w;
        }
    }
    float fr[HH * 3];
    {
        const float4* fp = reinterpret_cast<const float4*>(f + (size_t)b * (HH * 3));
#pragma unroll
        for (int j = 0; j < 15; ++j) {
            float4 v = fp[j];
            fr[4 * j + 0] = v.x; fr[4 * j + 1] = v.y;
            fr[4 * j + 2] = v.z; fr[4 * j + 3] = v.w;
        }
    }

    float acc = bo[0];

#pragma unroll
    for (int h = 0; h < HH; ++h) {
        // embedding gather (divergent -> LDS, <=13 distinct addrs/wave)
        int idx = er[h];
        float xv[8];
        xv[0] = s_emb[idx * 4 + 0];
        xv[1] = s_emb[idx * 4 + 1];
        xv[2] = s_emb[idx * 4 + 2];

        // features Linear 3->5 (Wf stored (in,out))
        float g0 = fr[h * 3 + 0], g1 = fr[h * 3 + 1], g2 = fr[h * 3 + 2];
#pragma unroll
        for (int o = 0; o < 5; ++o) {
            float a = bf[o];
            a = fmaf(g0, Wf[0 * 5 + o], a);
            a = fmaf(g1, Wf[1 * 5 + o], a);
            a = fmaf(g2, Wf[2 * 5 + o], a);
            xv[3 + o] = a;
        }

        // head MLP 8->10, leaky_relu, dot with W2 -> scalar
        float hacc = b2[h];
#pragma unroll
        for (int o = 0; o < 10; ++o) {
            float a = b1[h * 10 + o];
#pragma unroll
            for (int i = 0; i < 8; ++i)
                a = fmaf(xv[i], W1[(h * 8 + i) * 10 + o], a);
            a = fmaxf(a, 0.01f * a);               // leaky_relu, slope .01
            hacc = fmaf(a, W2[h * 10 + o], hacc);
        }

        // softplus = logaddexp(x, 0) = max(x,0) + log1p(exp(-|x|))
        float sp = fmaxf(hacc, 0.0f) + __logf(1.0f + __expf(-fabsf(hacc)));
        acc = fmaf(sp, Wo[h], acc);
    }

    out[b] = acc;
}

extern "C" void kernel_launch(void* const* d_in, const int* in_sizes, int n_in,
                              void* d_out, int out_size, void* d_ws, size_t ws_size,
                              hipStream_t stream) {
    const int*   e   = (const int*)  d_in[0];
    const float* f   = (const float*)d_in[1];
    const float* emb = (const float*)d_in[2];
    const float* Wf  = (const float*)d_in[3];
    const float* bf  = (const float*)d_in[4];
    const float* W1  = (const float*)d_in[5];
    const float* b1  = (const float*)d_in[6];
    const float* W2  = (const float*)d_in[7];
    const float* b2  = (const float*)d_in[8];
    const float* Wo  = (const float*)d_in[9];
    const float* bo  = (const float*)d_in[10];
    float* out = (float*)d_out;

    int B = in_sizes[0] / HH;          // e is (B, 20)
    int blocks = (B + 255) / 256;
    airfit_kernel<<<blocks, 256, 0, stream>>>(e, f, emb, Wf, bf, W1, b1,
                                              W2, b2, Wo, bo, out, B);
}